// Round 9
// baseline (32.229 us; speedup 1.0000x reference)
//
#include <hip/hip_runtime.h>
#include <stdint.h>

// out[b,p] = mean_d( probes[p,d] <= X[b,d] ? 1.0 : X[b,d] )
// B=2048, P=512, D=256, f32. SGPR-stream formulation (exact integer mask):
//   prep: Yt[u][b] = f2(1-x[b,2u], 1-x[b,2u+1])   (transposed, 2MB in d_ws)
//         Q1[p][d] = 2^24*(1-p) + 1               (exact int, 512KB in d_ws)
//   main: lane = b-row; y kept in 32 f2 VGPRs; q1 streamed via s_load (SGPR);
//         m2 = clamp(pk_fma(y2, -2^24, s_q1))  in {0,1}^2,  m=1 iff p<=x
//         acc2 += pk_fma(m2, y2)               (1 VALU instr per pair total)
//   out = (64*4 - ... ) -> (sx + sum m*y)/256, combined over 4 d-quarters.
// No LDS in the inner loop; scalar pipe feeds P operands in parallel.

#define BATCH  2048
#define NPROBE 512
#define DIM    256
#define NU     (DIM / 2)

typedef float f4 __attribute__((ext_vector_type(4)));
typedef float f2 __attribute__((ext_vector_type(2)));

#define YT_OFF   0
#define YT_BYTES (NU * BATCH * 8)            // 2 MB, f2[u][BATCH]
#define Q1_OFF   YT_BYTES
#define Q1_BYTES (NPROBE * DIM * 4)          // 512 KB, f32[p][d]
#define WS_NEED  ((size_t)(Q1_OFF + Q1_BYTES))

// ---------------- prep: build Yt (transpose of 1-x) and Q1 ----------------
__global__ __launch_bounds__(512)
void prep_kernel(const float* __restrict__ X, const float* __restrict__ Pr,
                 void* __restrict__ ws) {
  const int blk = blockIdx.x, t = threadIdx.x;
  if (blk < 128) {
    // 16 b x 256 d tile -> Yt[u][b] (f2 over d-pairs), LDS-tiled transpose
    f2* Yt = (f2*)((char*)ws + YT_OFF);
    __shared__ float yl[16 * 258];           // padded stride vs bank conflicts
    const int bb = blk * 16;
    #pragma unroll
    for (int s = 0; s < 2; ++s) {
      int idx = s * 512 + t;                 // f4 index in tile [0,1024)
      int r = idx >> 6, q = idx & 63;
      f4 v = *(const f4*)(X + (size_t)(bb + r) * DIM + 4 * q);
      f2 lo = {1.0f - v[0], 1.0f - v[1]};    // exact: x in [0,1)
      f2 hi = {1.0f - v[2], 1.0f - v[3]};
      *(f2*)&yl[r * 258 + 4 * q]     = lo;
      *(f2*)&yl[r * 258 + 4 * q + 2] = hi;
    }
    __syncthreads();
    #pragma unroll
    for (int s = 0; s < 4; ++s) {
      int o = s * 512 + t;                   // f2-out index [0,2048)
      int u = o >> 4, b = o & 15;
      f2 y = *(const f2*)&yl[b * 258 + 2 * u];
      Yt[(size_t)u * BATCH + bb + b] = y;
    }
  } else {
    // Q1 = 2^24*(1-p) + 1 (exact; p=0 rounds to 2^24, harmless)
    float* Q1 = (float*)((char*)ws + Q1_OFF);
    const float Kc = 16777216.0f;
    int gid = (blk - 128) * 512 + t;         // [0,16384)
    #pragma unroll
    for (int s = 0; s < 2; ++s) {
      int i = gid + s * 16384;               // f4 idx over 32768
      f4 p = *(const f4*)(Pr + (size_t)i * 4);
      f4 q;
      #pragma unroll
      for (int e = 0; e < 4; ++e)
        q[e] = __builtin_fmaf(p[e], -Kc, Kc) + 1.0f;
      *(f4*)(Q1 + (size_t)i * 4) = q;
    }
  }
}

// ---------------- main ----------------
__global__ __launch_bounds__(512, 4)
void yoneda_main(const void* __restrict__ ws, float* __restrict__ out) {
  const f2*    Yt = (const f2*)((const char*)ws + YT_OFF);
  const float* Q1 = (const float*)((const char*)ws + Q1_OFF);
  __shared__ float cb[8192];                 // combine buffer, 32 KB

  const int t  = threadIdx.x;
  const int l  = t & 63;                     // lane = b-row within tile
  const int wv = __builtin_amdgcn_readfirstlane(t >> 6);  // wave id 0..7
  const int ph = wv & 1;                     // p-half (16 probes)
  const int g2 = wv >> 1;                    // d-quarter (64 d = 32 pairs)
  const int b0 = blockIdx.y * 64, p0 = blockIdx.x * 32;

  // y for this lane's row, this wave's d-quarter: 32 f2, coalesced loads
  f2 y2[32];
  #pragma unroll
  for (int u = 0; u < 32; ++u)
    y2[u] = Yt[(size_t)(g2 * 32 + u) * BATCH + b0 + l];

  // sum_d x over the quarter = 64 - sum y
  f2 sy = {0.0f, 0.0f};
  #pragma unroll
  for (int u = 0; u < 32; ++u) sy += y2[u];
  const float sx = 64.0f - (sy[0] + sy[1]);

  const f2 mK2 = {-16777216.0f, -16777216.0f};

  #pragma unroll 1
  for (int pp = 0; pp < 16; ++pp) {
    const f2* qrow = (const f2*)(Q1 + ((p0 + ph * 16 + pp) << 8) + (g2 << 6));
    f2 a0 = {0.0f, 0.0f}, a1 = {0.0f, 0.0f};
    #pragma unroll
    for (int u = 0; u < 32; u += 2) {
      f2 q0 = qrow[u], q1v = qrow[u + 1];    // uniform -> s_load (SGPR pair)
      f2 m0, m1;
      asm("v_pk_fma_f32 %0, %1, %2, %3 clamp"
          : "=v"(m0) : "v"(y2[u]), "v"(mK2), "s"(q0));
      asm("v_pk_fma_f32 %0, %1, %2, %0"
          : "+v"(a0) : "v"(m0), "v"(y2[u]));
      asm("v_pk_fma_f32 %0, %1, %2, %3 clamp"
          : "=v"(m1) : "v"(y2[u + 1]), "v"(mK2), "s"(q1v));
      asm("v_pk_fma_f32 %0, %1, %2, %0"
          : "+v"(a1) : "v"(m1), "v"(y2[u + 1]));
    }
    float val = (a0[0] + a0[1]) + (a1[0] + a1[1]) + sx;
    // XOR-swizzled slot: writes 2-way (l, l+32) = free; fixed order
    cb[(g2 * 64 + l) * 32 + ((ph * 16 + pp) ^ (l & 31))] = val;
  }

  __syncthreads();
  const float inv = 1.0f / 256.0f;
  #pragma unroll
  for (int k = 0; k < 4; ++k) {
    int b = (t >> 5) + 16 * k;
    int p = t & 31;
    float v = 0.0f;
    #pragma unroll
    for (int gg = 0; gg < 4; ++gg)           // ascending -> deterministic
      v += cb[(gg * 64 + b) * 32 + (p ^ (b & 31))];
    out[(size_t)(b0 + b) * NPROBE + p0 + p] = v * inv;
  }
}

// ---------------- fallback (proven R2 kernel) if ws too small ----------------
static __device__ __forceinline__ void gl_lds16(const void* g, void* l) {
  __builtin_amdgcn_global_load_lds(
      (const __attribute__((address_space(1))) void*)g,
      (__attribute__((address_space(3))) void*)l, 16, 0, 0);
}

__global__ __launch_bounds__(1024)
void yoneda_f32_kernel(const float* __restrict__ X, const float* __restrict__ Pr,
                       float* __restrict__ out) {
  __shared__ float lds[32768];
  float* Xs = lds;
  float* Ps = lds + 16384;
  const int tid = threadIdx.x;
  const int b0 = blockIdx.y * 64, p0 = blockIdx.x * 64;
  #pragma unroll
  for (int s = 0; s < 4; ++s) {
    int idx = s * 1024 + tid;
    int r = idx >> 6, q = idx & 63;
    int qs = q ^ (r & 7);
    gl_lds16(X  + (size_t)(b0 + r) * DIM + 4 * qs, &Xs[idx * 4]);
    gl_lds16(Pr + (size_t)(p0 + r) * DIM + 4 * qs, &Ps[idx * 4]);
  }
  const int g = tid >> 8, gtid = tid & 255;
  const int tb = gtid >> 4, tp = gtid & 15;
  const int sxc = tb & 7, spc = tp & 7;
  const int qoff = g * 16;
  float acc[4][4];
  #pragma unroll
  for (int i = 0; i < 4; ++i)
    #pragma unroll
    for (int j = 0; j < 4; ++j) acc[i][j] = 0.0f;
  int xrow[4], prow[4];
  #pragma unroll
  for (int i = 0; i < 4; ++i) { xrow[i] = (tb + 16 * i) * DIM; prow[i] = (tp + 16 * i) * DIM; }
  __syncthreads();
  #pragma unroll 4
  for (int Q = 0; Q < 16; ++Q) {
    f4 xv[4], pv[4];
    #pragma unroll
    for (int i = 0; i < 4; ++i) xv[i] = *(const f4*)&Xs[xrow[i] + 4 * (qoff + (Q ^ sxc))];
    #pragma unroll
    for (int j = 0; j < 4; ++j) pv[j] = *(const f4*)&Ps[prow[j] + 4 * (qoff + (Q ^ spc))];
    #pragma unroll
    for (int i = 0; i < 4; ++i)
      #pragma unroll
      for (int j = 0; j < 4; ++j)
        #pragma unroll
        for (int e = 0; e < 4; ++e) {
          float x = xv[i][e], p = pv[j][e];
          acc[i][j] += (p <= x) ? 1.0f : x;
        }
  }
  __syncthreads();
  if (g > 0) {
    #pragma unroll
    for (int e = 0; e < 16; ++e)
      lds[(e * 3 + (g - 1)) * 256 + gtid] = acc[e >> 2][e & 3];
  }
  __syncthreads();
  if (g == 0) {
    const float inv = 1.0f / 256.0f;
    #pragma unroll
    for (int i = 0; i < 4; ++i) {
      size_t ro = (size_t)(b0 + tb + 16 * i) * NPROBE + p0 + tp;
      #pragma unroll
      for (int j = 0; j < 4; ++j) {
        const int e = i * 4 + j;
        float v = acc[i][j] + lds[(e * 3 + 0) * 256 + gtid]
                + lds[(e * 3 + 1) * 256 + gtid] + lds[(e * 3 + 2) * 256 + gtid];
        out[ro + 16 * j] = v * inv;
      }
    }
  }
}

extern "C" void kernel_launch(void* const* d_in, const int* in_sizes, int n_in,
                              void* d_out, int out_size, void* d_ws, size_t ws_size,
                              hipStream_t stream) {
  const float* X  = (const float*)d_in[0];   // (2048, 256) f32
  const float* Pr = (const float*)d_in[1];   // (512, 256)  f32
  float* out = (float*)d_out;                // (2048, 512) f32

  if (ws_size >= WS_NEED) {
    prep_kernel<<<160, 512, 0, stream>>>(X, Pr, d_ws);
    dim3 grid(NPROBE / 32, BATCH / 64);      // (16, 32) = 512 blocks, 2/CU
    yoneda_main<<<grid, 512, 0, stream>>>(d_ws, out);
  } else {
    dim3 grid(NPROBE / 64, BATCH / 64);
    yoneda_f32_kernel<<<grid, 1024, 0, stream>>>(X, Pr, out);
  }
}

// Round 10
// 22.069 us; speedup vs baseline: 1.4604x; 1.4604x over previous
//
#include <hip/hip_runtime.h>
#include <stdint.h>

// out[b,p] = mean_d( probes[p,d] <= X[b,d] ? 1.0 : X[b,d] )
// B=2048, P=512, D=256, f32. Exact-mask math (validated R6/R7/R8):
//   Y = 1-x (exact), Q1 = 2^24*(1-p)+1 (exact int)
//   m2 = clamp(pk_fma(y, -2^24, q1)) = clamp(2^24(x-p)+1) in {0,1}, 1 iff p<=x
//   acc += m*y ;  partial(group) = (32 - sum y) + sum m*y ;  out = sum/256
// R10: occupancy 8 -> 16 waves/CU. 1024-thr block, 8x4 packed tile
// (VGPR <= 128 via __launch_bounds__(1024,4)), transforms folded into
// staging, XOR swizzle on write+read, balanced combine with XOR-fold map.

#define BATCH  2048
#define NPROBE 512
#define DIM    256

typedef float f4 __attribute__((ext_vector_type(4)));
typedef float f2 __attribute__((ext_vector_type(2)));

__global__ __launch_bounds__(1024, 4)
void yoneda_kernel(const float* __restrict__ X, const float* __restrict__ Pr,
                   float* __restrict__ out) {
  // 128 KiB: Y [64 rows][256 f32] | Q1 [64 rows][256 f32]; overlay cbuf[8][4096]
  __shared__ float lds[32768];

  const int tid = threadIdx.x;
  const int b0 = blockIdx.y * 64, p0 = blockIdx.x * 64;
  const float K = 16777216.0f;       // 2^24

  // ---- stage with transforms; write-side XOR swizzle: slot = q ^ (r&7) (low 3 bits)
  #pragma unroll
  for (int s = 0; s < 4; ++s) {
    int idx = s * 1024 + tid;        // quad index [0,4096)
    int r = idx >> 6, q = idx & 63;
    int slot = (q & 56) | ((q ^ r) & 7);
    f4 xv = *(const f4*)(X  + (size_t)(b0 + r) * DIM + 4 * q);
    f4 pv = *(const f4*)(Pr + (size_t)(p0 + r) * DIM + 4 * q);
    f4 yv, qv;
    #pragma unroll
    for (int e = 0; e < 4; ++e) {
      yv[e] = 1.0f - xv[e];                              // exact
      qv[e] = __builtin_fmaf(pv[e], -K, K) + 1.0f;       // exact int (p=0 benign)
    }
    *(f4*)&lds[r * 256 + 4 * slot]         = yv;
    *(f4*)&lds[16384 + r * 256 + 4 * slot] = qv;
  }

  const int wv   = tid >> 6;         // wave 0..15
  const int g2   = wv >> 1;          // d-group 0..7 (32 d = 8 quads)
  const int ph   = wv & 1;           // p-half (32 cols)
  const int gtid = tid & 63;
  const int tb   = gtid >> 3;        // rows tb+8i, i<8
  const int tp   = gtid & 7;         // cols ph*32 + tp+8j, j<4

  int xrow[8], prow[4];
  #pragma unroll
  for (int i = 0; i < 8; ++i) xrow[i] = (tb + 8 * i) * 256 + g2 * 32;
  #pragma unroll
  for (int j = 0; j < 4; ++j) prow[j] = 16384 + (ph * 32 + tp + 8 * j) * 256 + g2 * 32;

  f2 acc2[8][4], accy2[8];
  #pragma unroll
  for (int i = 0; i < 8; ++i) {
    accy2[i] = (f2){0.0f, 0.0f};
    #pragma unroll
    for (int j = 0; j < 4; ++j) acc2[i][j] = (f2){0.0f, 0.0f};
  }
  const f2 mK2 = {-K, -K};

  __syncthreads();                   // staging visible to all

  #pragma unroll 1
  for (int s = 0; s < 8; ++s) {
    const int xo = 4 * (s ^ tb);     // read-side un-swizzle (row&7 == tb / tp)
    const int po = 4 * (s ^ tp);
    f4 pv[4];
    #pragma unroll
    for (int j = 0; j < 4; ++j) pv[j] = *(const f4*)&lds[prow[j] + po];
    #pragma unroll
    for (int i = 0; i < 8; ++i) {
      f4 yv = *(const f4*)&lds[xrow[i] + xo];
      f2 ya = {yv[0], yv[1]}, yc = {yv[2], yv[3]};
      accy2[i] += ya;
      accy2[i] += yc;
      #pragma unroll
      for (int j = 0; j < 4; ++j) {
        f2 pa = {pv[j][0], pv[j][1]}, pc = {pv[j][2], pv[j][3]};
        f2 ma, mc;
        asm("v_pk_fma_f32 %0, %1, %2, %3 clamp"
            : "=v"(ma) : "v"(ya), "v"(mK2), "v"(pa));
        asm("v_pk_fma_f32 %0, %1, %2, %0"
            : "+v"(acc2[i][j]) : "v"(ma), "v"(ya));
        asm("v_pk_fma_f32 %0, %1, %2, %3 clamp"
            : "=v"(mc) : "v"(yc), "v"(mK2), "v"(pc));
        asm("v_pk_fma_f32 %0, %1, %2, %0"
            : "+v"(acc2[i][j]) : "v"(mc), "v"(yc));
      }
    }
  }

  // ---- combine 8 d-group partials via 128 KiB overlay; XOR-fold addressing:
  // addr(o,g) = g*4096 + (o ^ ((row&7)<<2)); write <=2-way, read paired b64.
  __syncthreads();                   // all tile reads done
  const int tbx   = tb << 2;
  const int obase = tb * 64 + ph * 32 + tp;
  const int gseg  = g2 << 12;
  #pragma unroll
  for (int i = 0; i < 8; ++i) {
    float sxg = 32.0f - (accy2[i][0] + accy2[i][1]);   // Sum_group x = 32 - Sum y
    #pragma unroll
    for (int j = 0; j < 4; ++j) {
      int o = obase + 512 * i + 8 * j;                 // o = row*64 + col
      lds[gseg + (o ^ tbx)] = sxg + acc2[i][j][0] + acc2[i][j][1];
    }
  }
  __syncthreads();
  const float inv  = 1.0f / 256.0f;
  const int   fold = ((tid >> 5) & 7) << 2;            // == ((o>>6)&7)<<2 for both k
  #pragma unroll
  for (int k = 0; k < 2; ++k) {
    int o = 2 * (k * 1024 + tid);    // output pair (o, o+1)
    int a = o ^ fold;                // bit0 untouched -> b64-contiguous
    f2 v = *(const f2*)&lds[a];      // g=0
    #pragma unroll
    for (int g = 1; g < 8; ++g)      // ascending order -> deterministic
      v += *(const f2*)&lds[(g << 12) + a];
    v *= inv;
    int row = o >> 6, col = o & 63;
    *(f2*)&out[(size_t)(b0 + row) * NPROBE + p0 + col] = v;  // coalesced dwordx2
  }
}

extern "C" void kernel_launch(void* const* d_in, const int* in_sizes, int n_in,
                              void* d_out, int out_size, void* d_ws, size_t ws_size,
                              hipStream_t stream) {
  const float* X  = (const float*)d_in[0];   // (2048, 256) f32
  const float* Pr = (const float*)d_in[1];   // (512, 256)  f32
  float* outp = (float*)d_out;               // (2048, 512) f32
  dim3 grid(NPROBE / 64, BATCH / 64);        // (8, 32) = 256 blocks, 1/CU
  yoneda_kernel<<<grid, 1024, 0, stream>>>(X, Pr, outp);
}

// Round 11
// 21.982 us; speedup vs baseline: 1.4661x; 1.0039x over previous
//
#include <hip/hip_runtime.h>
#include <stdint.h>

// out[b,p] = mean_d( probes[p,d] <= X[b,d] ? 1.0 : X[b,d] )
// B=2048, P=512, D=256, f32. Exact-mask math (validated R6/R7/R8/R10):
//   Y = 1-x (exact), Q1 = 2^24*(1-p)+1 (exact int)
//   m2 = clamp(pk_fma(y, -2^24, q1)) = clamp(2^24(x-p)+1) in {0,1}, 1 iff p<=x
//   acc += m*y ;  partial(group) = (32 - sum y) + sum m*y ;  out = sum/256
// R11 (= R10 + two scheduling changes, single-hypothesis test):
//   (i)  per-wave step rotation s = (s0+wv)&7  -> de-phase the waves' LDS
//        read bursts vs FMA clusters (lockstep-collision hypothesis)
//   (ii) s_setprio(1) around the FMA cluster (T5; rotation gives the
//        scheduler role diversity to arbitrate)

#define BATCH  2048
#define NPROBE 512
#define DIM    256

typedef float f4 __attribute__((ext_vector_type(4)));
typedef float f2 __attribute__((ext_vector_type(2)));

__global__ __launch_bounds__(1024, 4)
void yoneda_kernel(const float* __restrict__ X, const float* __restrict__ Pr,
                   float* __restrict__ out) {
  // 128 KiB: Y [64 rows][256 f32] | Q1 [64 rows][256 f32]; overlay cbuf[8][4096]
  __shared__ float lds[32768];

  const int tid = threadIdx.x;
  const int b0 = blockIdx.y * 64, p0 = blockIdx.x * 64;
  const float K = 16777216.0f;       // 2^24

  // ---- stage with transforms; write-side XOR swizzle: slot = q ^ (r&7) (low 3 bits)
  #pragma unroll
  for (int s = 0; s < 4; ++s) {
    int idx = s * 1024 + tid;        // quad index [0,4096)
    int r = idx >> 6, q = idx & 63;
    int slot = (q & 56) | ((q ^ r) & 7);
    f4 xv = *(const f4*)(X  + (size_t)(b0 + r) * DIM + 4 * q);
    f4 pv = *(const f4*)(Pr + (size_t)(p0 + r) * DIM + 4 * q);
    f4 yv, qv;
    #pragma unroll
    for (int e = 0; e < 4; ++e) {
      yv[e] = 1.0f - xv[e];                              // exact
      qv[e] = __builtin_fmaf(pv[e], -K, K) + 1.0f;       // exact int (p=0 benign)
    }
    *(f4*)&lds[r * 256 + 4 * slot]         = yv;
    *(f4*)&lds[16384 + r * 256 + 4 * slot] = qv;
  }

  const int wv   = tid >> 6;         // wave 0..15
  const int g2   = wv >> 1;          // d-group 0..7 (32 d = 8 quads)
  const int ph   = wv & 1;           // p-half (32 cols)
  const int gtid = tid & 63;
  const int tb   = gtid >> 3;        // rows tb+8i, i<8
  const int tp   = gtid & 7;         // cols ph*32 + tp+8j, j<4

  int xrow[8], prow[4];
  #pragma unroll
  for (int i = 0; i < 8; ++i) xrow[i] = (tb + 8 * i) * 256 + g2 * 32;
  #pragma unroll
  for (int j = 0; j < 4; ++j) prow[j] = 16384 + (ph * 32 + tp + 8 * j) * 256 + g2 * 32;

  f2 acc2[8][4], accy2[8];
  #pragma unroll
  for (int i = 0; i < 8; ++i) {
    accy2[i] = (f2){0.0f, 0.0f};
    #pragma unroll
    for (int j = 0; j < 4; ++j) acc2[i][j] = (f2){0.0f, 0.0f};
  }
  const f2 mK2 = {-K, -K};

  __syncthreads();                   // staging visible to all

  #pragma unroll 1
  for (int s0 = 0; s0 < 8; ++s0) {
    const int s  = (s0 + wv) & 7;    // (i) de-lockstep: per-wave step rotation
    const int xo = 4 * (s ^ tb);     // read-side un-swizzle (row&7 == tb / tp)
    const int po = 4 * (s ^ tp);
    f4 pv[4];
    #pragma unroll
    for (int j = 0; j < 4; ++j) pv[j] = *(const f4*)&lds[prow[j] + po];
    __builtin_amdgcn_s_setprio(1);   // (ii) favor the FMA cluster
    #pragma unroll
    for (int i = 0; i < 8; ++i) {
      f4 yv = *(const f4*)&lds[xrow[i] + xo];
      f2 ya = {yv[0], yv[1]}, yc = {yv[2], yv[3]};
      accy2[i] += ya;
      accy2[i] += yc;
      #pragma unroll
      for (int j = 0; j < 4; ++j) {
        f2 pa = {pv[j][0], pv[j][1]}, pc = {pv[j][2], pv[j][3]};
        f2 ma, mc;
        asm("v_pk_fma_f32 %0, %1, %2, %3 clamp"
            : "=v"(ma) : "v"(ya), "v"(mK2), "v"(pa));
        asm("v_pk_fma_f32 %0, %1, %2, %0"
            : "+v"(acc2[i][j]) : "v"(ma), "v"(ya));
        asm("v_pk_fma_f32 %0, %1, %2, %3 clamp"
            : "=v"(mc) : "v"(yc), "v"(mK2), "v"(pc));
        asm("v_pk_fma_f32 %0, %1, %2, %0"
            : "+v"(acc2[i][j]) : "v"(mc), "v"(yc));
      }
    }
    __builtin_amdgcn_s_setprio(0);
  }

  // ---- combine 8 d-group partials via 128 KiB overlay; XOR-fold addressing:
  // addr(o,g) = g*4096 + (o ^ ((row&7)<<2)); write <=2-way, read paired b64.
  __syncthreads();                   // all tile reads done
  const int tbx   = tb << 2;
  const int obase = tb * 64 + ph * 32 + tp;
  const int gseg  = g2 << 12;
  #pragma unroll
  for (int i = 0; i < 8; ++i) {
    float sxg = 32.0f - (accy2[i][0] + accy2[i][1]);   // Sum_group x = 32 - Sum y
    #pragma unroll
    for (int j = 0; j < 4; ++j) {
      int o = obase + 512 * i + 8 * j;                 // o = row*64 + col
      lds[gseg + (o ^ tbx)] = sxg + acc2[i][j][0] + acc2[i][j][1];
    }
  }
  __syncthreads();
  const float inv  = 1.0f / 256.0f;
  const int   fold = ((tid >> 5) & 7) << 2;            // == ((o>>6)&7)<<2 for both k
  #pragma unroll
  for (int k = 0; k < 2; ++k) {
    int o = 2 * (k * 1024 + tid);    // output pair (o, o+1)
    int a = o ^ fold;                // bit0 untouched -> b64-contiguous
    f2 v = *(const f2*)&lds[a];      // g=0
    #pragma unroll
    for (int g = 1; g < 8; ++g)      // ascending order -> deterministic
      v += *(const f2*)&lds[(g << 12) + a];
    v *= inv;
    int row = o >> 6, col = o & 63;
    *(f2*)&out[(size_t)(b0 + row) * NPROBE + p0 + col] = v;  // coalesced dwordx2
  }
}

extern "C" void kernel_launch(void* const* d_in, const int* in_sizes, int n_in,
                              void* d_out, int out_size, void* d_ws, size_t ws_size,
                              hipStream_t stream) {
  const float* X  = (const float*)d_in[0];   // (2048, 256) f32
  const float* Pr = (const float*)d_in[1];   // (512, 256)  f32
  float* outp = (float*)d_out;               // (2048, 512) f32
  dim3 grid(NPROBE / 64, BATCH / 64);        // (8, 32) = 256 blocks, 1/CU
  yoneda_kernel<<<grid, 1024, 0, stream>>>(X, Pr, outp);
}